// Round 4
// baseline (1394.391 us; speedup 1.0000x reference)
//
#include <hip/hip_runtime.h>
#include <hip/hip_bf16.h>
#include <math.h>

// ---- problem constants ----
#define D_  768
#define T_  1024
#define B_  2
#define H_  12
#define HD_ 64
#define L_  8
#define F_  3072
#define V_  1024
#define M_  (B_ * T_)   // 2048 rows of activations

typedef __bf16 bf16_t;
typedef __bf16 bf16x8 __attribute__((ext_vector_type(8)));
typedef float  f32x4  __attribute__((ext_vector_type(4)));

// async 16B global->LDS (direct DMA, lane i lands at lds_base + i*16)
__device__ __forceinline__ void ld_g2l16(const bf16_t* g, bf16_t* l)
{
    __builtin_amdgcn_global_load_lds(
        (const __attribute__((address_space(1))) void*)g,
        (__attribute__((address_space(3))) void*)l,
        16, 0, 0);
}

// ---------------- embed: x = tok_emb[ids] + pos_emb (all f32) ----------------
__global__ __launch_bounds__(256) void embed_kernel(
    const int* __restrict__ ids, const float* __restrict__ tok,
    const float* __restrict__ pos, float* __restrict__ x)
{
    const int row = blockIdx.x;          // b*T + t
    const int t   = row & (T_ - 1);
    const int id  = ids[row];
    const int c   = threadIdx.x;
#pragma unroll
    for (int i = 0; i < 3; ++i) {
        const int d = c + i * 256;
        x[(size_t)row * D_ + d] = tok[(size_t)id * D_ + d] + pos[(size_t)t * D_ + d];
    }
}

// ------- weight transpose+convert: f32 [K][N] -> bf16 [N][K], per-layer via z -------
__global__ __launch_bounds__(256) void wtrans_kernel(
    const float* __restrict__ in, bf16_t* __restrict__ out, int K, int N)
{
    __shared__ float tile[32][33];
    const size_t loff = (size_t)blockIdx.z * K * N;
    const float* inp  = in  + loff;
    bf16_t*      outp = out + loff;
    const int n0 = blockIdx.x * 32, k0 = blockIdx.y * 32;
    const int tx = threadIdx.x & 31, ty = threadIdx.x >> 5;   // ty 0..7
#pragma unroll
    for (int i = 0; i < 4; ++i)
        tile[ty + 8 * i][tx] = inp[(size_t)(k0 + ty + 8 * i) * N + n0 + tx];
    __syncthreads();
#pragma unroll
    for (int i = 0; i < 4; ++i) {
        const int n = ty + 8 * i;
        outp[(size_t)(n0 + n) * K + k0 + tx] = (bf16_t)tile[tx][n];
    }
}

// ---------------- straight convert f32 -> bf16 (tok_emb for lm_head) ----------------
__global__ __launch_bounds__(256) void conv_kernel(
    const float* __restrict__ in, bf16_t* __restrict__ out)
{
    const int i = blockIdx.x * 1024 + threadIdx.x * 4;
    const f32x4 v = *(const f32x4*)(in + i);
#pragma unroll
    for (int j = 0; j < 4; ++j) out[i + j] = (bf16_t)v[j];
}

// ---------------- layernorm: f32 in -> bf16 out ----------------
__device__ __forceinline__ float block_sum(float v)
{
    __shared__ float sm[4];
#pragma unroll
    for (int off = 32; off; off >>= 1) v += __shfl_down(v, off);
    if ((threadIdx.x & 63) == 0) sm[threadIdx.x >> 6] = v;
    __syncthreads();
    const float r = sm[0] + sm[1] + sm[2] + sm[3];
    __syncthreads();
    return r;
}

__global__ __launch_bounds__(256) void ln_kernel(
    const float* __restrict__ x, const float* __restrict__ w,
    const float* __restrict__ b, bf16_t* __restrict__ out)
{
    const int row = blockIdx.x;
    const float* xr = x + (size_t)row * D_;
    const int t = threadIdx.x;
    const float v0 = xr[t];
    const float v1 = xr[t + 256];
    const float v2 = xr[t + 512];
    const float mu = block_sum(v0 + v1 + v2) * (1.f / D_);
    const float d0 = v0 - mu, d1 = v1 - mu, d2 = v2 - mu;
    const float var = block_sum(d0 * d0 + d1 * d1 + d2 * d2) * (1.f / D_);
    const float rstd = rsqrtf(var + 1e-5f);
    bf16_t* o = out + (size_t)row * D_;
    o[t]       = (bf16_t)(d0 * rstd * w[t]       + b[t]);
    o[t + 256] = (bf16_t)(d1 * rstd * w[t + 256] + b[t + 256]);
    o[t + 512] = (bf16_t)(d2 * rstd * w[t + 512] + b[t + 512]);
}

// ---------------- GEMM 64-row (B^T bf16): C = act(A @ Bt^T + bias + res) ----------
// BM=64, BK=64, BN in {64,128}; 4 waves in 2x2 quadrants, each wave 32 x BN/2.
// global_load_lds w=16, XOR-8 16B-chunk swizzle (row r chunk c at slot c^(r&7)).
// MFMA layouts (m89/m91): A/B frag idx=lane&15, k=quad*8+j; D row=quad*4+reg, col=lane&15.
template<int BN, bool RES, bool BIAS, bool GELU_, bool OUTF32>
__global__ __launch_bounds__(256) void gemm_bt(
    const bf16_t* __restrict__ A, const bf16_t* __restrict__ Bt,
    const float* __restrict__ bias, const float* __restrict__ res,
    void* __restrict__ Cp, int M, int N, int K)
{
    constexpr int BM = 64, BK = 64;
    constexpr int WN = BN / 2, NT = WN / 16;
    constexpr int AR = (BM * BK) / (256 * 8);
    constexpr int BR = (BN * BK) / (256 * 8);
    __shared__ bf16_t As[BM * BK];
    __shared__ bf16_t Bs[BN * BK];

    const int t    = threadIdx.x;
    const int wave = t >> 6, lane = t & 63;
    const int lr   = lane & 15, quad = lane >> 4;
    const int bm0  = blockIdx.y * BM, bn0 = blockIdx.x * BN;
    const int wm   = wave >> 1, wn = wave & 1;

    f32x4 acc[2][NT];
#pragma unroll
    for (int i = 0; i < 2; ++i)
#pragma unroll
        for (int j = 0; j < NT; ++j) { f32x4 z = {0.f, 0.f, 0.f, 0.f}; acc[i][j] = z; }

    const bf16_t* asrc[AR];
    const bf16_t* bsrc[BR];
#pragma unroll
    for (int rnd = 0; rnd < AR; ++rnd) {
        const int p = rnd * 256 + t, row = p >> 3, c = (p & 7) ^ (row & 7);
        asrc[rnd] = A + (size_t)(bm0 + row) * K + c * 8;
    }
#pragma unroll
    for (int rnd = 0; rnd < BR; ++rnd) {
        const int p = rnd * 256 + t, row = p >> 3, c = (p & 7) ^ (row & 7);
        bsrc[rnd] = Bt + (size_t)(bn0 + row) * K + c * 8;
    }

    for (int k0 = 0; k0 < K; k0 += BK) {
        __syncthreads();
#pragma unroll
        for (int rnd = 0; rnd < AR; ++rnd)
            ld_g2l16(asrc[rnd] + k0, As + (rnd * 256 + wave * 64) * 8);
#pragma unroll
        for (int rnd = 0; rnd < BR; ++rnd)
            ld_g2l16(bsrc[rnd] + k0, Bs + (rnd * 256 + wave * 64) * 8);
        __syncthreads();

#pragma unroll
        for (int ks = 0; ks < 2; ++ks) {
            const int ch = ((quad + 4 * ks) ^ (lr & 7)) * 8;
            const bf16x8 a0 = *(const bf16x8*)(As + (wm * 32 + lr) * BK + ch);
            const bf16x8 a1 = *(const bf16x8*)(As + (wm * 32 + 16 + lr) * BK + ch);
#pragma unroll
            for (int nt = 0; nt < NT; ++nt) {
                const bf16x8 b = *(const bf16x8*)(Bs + (wn * WN + nt * 16 + lr) * BK + ch);
                acc[0][nt] = __builtin_amdgcn_mfma_f32_16x16x32_bf16(a0, b, acc[0][nt], 0, 0, 0);
                acc[1][nt] = __builtin_amdgcn_mfma_f32_16x16x32_bf16(a1, b, acc[1][nt], 0, 0, 0);
            }
        }
    }

#pragma unroll
    for (int mt = 0; mt < 2; ++mt) {
        const int mbase = bm0 + wm * 32 + mt * 16 + quad * 4;
#pragma unroll
        for (int nt = 0; nt < NT; ++nt) {
            const int n = bn0 + wn * WN + nt * 16 + lr;
            const float bv = BIAS ? bias[n] : 0.f;
#pragma unroll
            for (int r = 0; r < 4; ++r) {
                const int m = mbase + r;
                float v = acc[mt][nt][r] + bv;
                if (RES)   v += res[(size_t)m * N + n];
                if (GELU_) v = 0.5f * v * (1.f + erff(v * 0.70710678118654752f));
                if (OUTF32) ((float*)Cp)[(size_t)m * N + n] = v;
                else        ((bf16_t*)Cp)[(size_t)m * N + n] = (bf16_t)v;
            }
        }
    }
}

// ---------------- GEMM 128x128 (m97 structure): C = act(A @ Bt^T + bias) ----------
// BM=BN=128, BK=64; 4 waves 2x2, each wave 64x64 (4x4 16x16 frags).
// Per K-step/wave: 16 ds_read_b128 vs 32 MFMA (ratio 1.2:1 vs 1.85:1 at 64-tile).
template<bool BIAS, bool GELU_>
__global__ __launch_bounds__(256) void gemm_bt128(
    const bf16_t* __restrict__ A, const bf16_t* __restrict__ Bt,
    const float* __restrict__ bias, bf16_t* __restrict__ C,
    int M, int N, int K)
{
    constexpr int BM = 128, BN = 128, BK = 64;
    __shared__ bf16_t As[BM * BK];   // 16 KB
    __shared__ bf16_t Bs[BN * BK];   // 16 KB

    const int t    = threadIdx.x;
    const int wave = t >> 6, lane = t & 63;
    const int lr   = lane & 15, quad = lane >> 4;
    const int bm0  = blockIdx.y * BM, bn0 = blockIdx.x * BN;
    const int wm   = wave >> 1, wn = wave & 1;     // 64-row, 64-col wave tile

    f32x4 acc[4][4];
#pragma unroll
    for (int i = 0; i < 4; ++i)
#pragma unroll
        for (int j = 0; j < 4; ++j) { f32x4 z = {0.f, 0.f, 0.f, 0.f}; acc[i][j] = z; }

    // 4 staging rounds each for A and B (1024 lane-blocks of 8 elems = 128x64)
    const bf16_t* asrc[4];
    const bf16_t* bsrc[4];
#pragma unroll
    for (int rnd = 0; rnd < 4; ++rnd) {
        const int p = rnd * 256 + t, row = p >> 3, c = (p & 7) ^ (row & 7);
        asrc[rnd] = A  + (size_t)(bm0 + row) * K + c * 8;
        bsrc[rnd] = Bt + (size_t)(bn0 + row) * K + c * 8;
    }

    for (int k0 = 0; k0 < K; k0 += BK) {
        __syncthreads();
#pragma unroll
        for (int rnd = 0; rnd < 4; ++rnd)
            ld_g2l16(asrc[rnd] + k0, As + (rnd * 256 + wave * 64) * 8);
#pragma unroll
        for (int rnd = 0; rnd < 4; ++rnd)
            ld_g2l16(bsrc[rnd] + k0, Bs + (rnd * 256 + wave * 64) * 8);
        __syncthreads();

#pragma unroll
        for (int ks = 0; ks < 2; ++ks) {
            const int ch = ((quad + 4 * ks) ^ (lr & 7)) * 8;
            bf16x8 a[4];
#pragma unroll
            for (int mt = 0; mt < 4; ++mt)
                a[mt] = *(const bf16x8*)(As + (wm * 64 + mt * 16 + lr) * BK + ch);
#pragma unroll
            for (int nt = 0; nt < 4; ++nt) {
                const bf16x8 b = *(const bf16x8*)(Bs + (wn * 64 + nt * 16 + lr) * BK + ch);
#pragma unroll
                for (int mt = 0; mt < 4; ++mt)
                    acc[mt][nt] = __builtin_amdgcn_mfma_f32_16x16x32_bf16(a[mt], b, acc[mt][nt], 0, 0, 0);
            }
        }
    }

#pragma unroll
    for (int mt = 0; mt < 4; ++mt) {
        const int mbase = bm0 + wm * 64 + mt * 16 + quad * 4;
#pragma unroll
        for (int nt = 0; nt < 4; ++nt) {
            const int n = bn0 + wn * 64 + nt * 16 + lr;
            const float bv = BIAS ? bias[n] : 0.f;
#pragma unroll
            for (int r = 0; r < 4; ++r) {
                float v = acc[mt][nt][r] + bv;
                if (GELU_) v = 0.5f * v * (1.f + erff(v * 0.70710678118654752f));
                C[(size_t)(mbase + r) * N + n] = (bf16_t)v;
            }
        }
    }
}

// ---------------- flash attention, MFMA ----------------
// v4: v3 (T14 register prefetch) + heavy-tile-first dispatch: causal block work
// scales with q-tile index, so map blockIdx.x -> reversed q-tile. Late-dispatched
// blocks are the light ones -> shorter tail on 384 blocks / 256 CUs.
__global__ __launch_bounds__(256) void attn_kernel(
    const bf16_t* __restrict__ qkv, bf16_t* __restrict__ y)
{
    __shared__ bf16_t Ks[64][72];
    __shared__ bf16_t Vt[64][72];
    __shared__ bf16_t Ps[4][16][72];

    const int qt   = (int)gridDim.x - 1 - (int)blockIdx.x;   // heavy first
    const int q0   = qt * 64;
    const int bh   = blockIdx.y;
    const int b    = bh / H_;
    const int hh   = bh % H_;
    const int t    = threadIdx.x;
    const int wave = t >> 6;
    const int lane = t & 63;
    const int lr   = lane & 15;
    const int quad = lane >> 4;

    const size_t qg = ((size_t)b * T_ + q0 + wave * 16 + lr) * (3 * D_) + hh * HD_;
    const bf16x8 aQ0 = *(const bf16x8*)(qkv + qg + quad * 8);
    const bf16x8 aQ1 = *(const bf16x8*)(qkv + qg + 32 + quad * 8);

    const size_t rowb  = (size_t)b * T_;
    const size_t tstep = (size_t)64 * 3 * D_;
    const int    kkey  = t >> 2, kdc = (t & 3) * 8;
    const bf16_t* kptr = qkv + (rowb + kkey) * (3 * D_) + D_ + hh * HD_ + kdc;
    const bf16_t* vptr = qkv + (rowb + lane) * (3 * D_) + 2 * D_ + hh * HD_ + wave * 16;

    bf16x8 rk0 = *(const bf16x8*)(kptr);
    bf16x8 rk1 = *(const bf16x8*)(kptr + 32);
    bf16x8 rv0 = *(const bf16x8*)(vptr);
    bf16x8 rv1 = *(const bf16x8*)(vptr + 8);

    f32x4 o[4];
#pragma unroll
    for (int i = 0; i < 4; ++i) { f32x4 z = {0.f, 0.f, 0.f, 0.f}; o[i] = z; }
    float mrow[4] = {-1e30f, -1e30f, -1e30f, -1e30f};
    float lrow[4] = {0.f, 0.f, 0.f, 0.f};

    for (int kt = 0; kt <= qt; ++kt) {
        const int k_base = kt * 64;
        __syncthreads();

        *(bf16x8*)(&Ks[kkey][kdc])      = rk0;
        *(bf16x8*)(&Ks[kkey][kdc + 32]) = rk1;
#pragma unroll
        for (int i = 0; i < 8; ++i) {
            Vt[wave * 16 + i][lane]     = rv0[i];
            Vt[wave * 16 + 8 + i][lane] = rv1[i];
        }
        __syncthreads();

        if (kt < qt) {
            const bf16_t* kp = kptr + (size_t)(kt + 1) * tstep;
            const bf16_t* vp = vptr + (size_t)(kt + 1) * tstep;
            rk0 = *(const bf16x8*)(kp);
            rk1 = *(const bf16x8*)(kp + 32);
            rv0 = *(const bf16x8*)(vp);
            rv1 = *(const bf16x8*)(vp + 8);
        }

        f32x4 s[4];
#pragma unroll
        for (int i = 0; i < 4; ++i) { f32x4 z = {0.f, 0.f, 0.f, 0.f}; s[i] = z; }
#pragma unroll
        for (int nt = 0; nt < 4; ++nt) {
            bf16x8 bk0 = *(const bf16x8*)(&Ks[nt * 16 + lr][quad * 8]);
            bf16x8 bk1 = *(const bf16x8*)(&Ks[nt * 16 + lr][32 + quad * 8]);
            s[nt] = __builtin_amdgcn_mfma_f32_16x16x32_bf16(aQ0, bk0, s[nt], 0, 0, 0);
            s[nt] = __builtin_amdgcn_mfma_f32_16x16x32_bf16(aQ1, bk1, s[nt], 0, 0, 0);
        }

#pragma unroll
        for (int r = 0; r < 4; ++r) {
            const int qg_i = q0 + wave * 16 + quad * 4 + r;
            float mx = -1e30f;
#pragma unroll
            for (int nt = 0; nt < 4; ++nt) {
                float sv = s[nt][r] * 0.125f;
                if (k_base + nt * 16 + lr > qg_i) sv = -1e30f;
                s[nt][r] = sv;
                mx = fmaxf(mx, sv);
            }
            mx = fmaxf(mx, __shfl_xor(mx, 1));
            mx = fmaxf(mx, __shfl_xor(mx, 2));
            mx = fmaxf(mx, __shfl_xor(mx, 4));
            mx = fmaxf(mx, __shfl_xor(mx, 8));
            const float mnew = fmaxf(mrow[r], mx);
            float ps = 0.f;
#pragma unroll
            for (int nt = 0; nt < 4; ++nt) {
                const float p = __expf(s[nt][r] - mnew);
                s[nt][r] = p;
                ps += p;
            }
            ps += __shfl_xor(ps, 1);
            ps += __shfl_xor(ps, 2);
            ps += __shfl_xor(ps, 4);
            ps += __shfl_xor(ps, 8);
            const float alpha = __expf(mrow[r] - mnew);
            lrow[r] = lrow[r] * alpha + ps;
            mrow[r] = mnew;
#pragma unroll
            for (int nt = 0; nt < 4; ++nt) o[nt][r] *= alpha;
        }

#pragma unroll
        for (int nt = 0; nt < 4; ++nt)
#pragma unroll
            for (int r = 0; r < 4; ++r)
                Ps[wave][quad * 4 + r][nt * 16 + lr] = (bf16_t)s[nt][r];

        const bf16x8 aP0 = *(const bf16x8*)(&Ps[wave][lr][quad * 8]);
        const bf16x8 aP1 = *(const bf16x8*)(&Ps[wave][lr][32 + quad * 8]);
#pragma unroll
        for (int nt = 0; nt < 4; ++nt) {
            bf16x8 bv0 = *(const bf16x8*)(&Vt[nt * 16 + lr][quad * 8]);
            bf16x8 bv1 = *(const bf16x8*)(&Vt[nt * 16 + lr][32 + quad * 8]);
            o[nt] = __builtin_amdgcn_mfma_f32_16x16x32_bf16(aP0, bv0, o[nt], 0, 0, 0);
            o[nt] = __builtin_amdgcn_mfma_f32_16x16x32_bf16(aP1, bv1, o[nt], 0, 0, 0);
        }
    }

#pragma unroll
    for (int r = 0; r < 4; ++r) {
        const float inv = 1.f / lrow[r];
        const size_t row = (size_t)b * T_ + q0 + wave * 16 + quad * 4 + r;
#pragma unroll
        for (int nt = 0; nt < 4; ++nt)
            y[row * D_ + hh * HD_ + nt * 16 + lr] = (bf16_t)(o[nt][r] * inv);
    }
}

// ---------------- launch ----------------
extern "C" void kernel_launch(void* const* d_in, const int* in_sizes, int n_in,
                              void* d_out, int out_size, void* d_ws, size_t ws_size,
                              hipStream_t stream)
{
    const int*   ids  = (const int*)d_in[0];
    const float* tok  = (const float*)d_in[1];
    const float* pos  = (const float*)d_in[2];
    const float* l1w  = (const float*)d_in[3];
    const float* l1b  = (const float*)d_in[4];
    const float* qkvw = (const float*)d_in[5];
    const float* outw = (const float*)d_in[6];
    const float* l2w  = (const float*)d_in[7];
    const float* l2b  = (const float*)d_in[8];
    const float* w1   = (const float*)d_in[9];
    const float* b1   = (const float*)d_in[10];
    const float* w2   = (const float*)d_in[11];
    const float* b2   = (const float*)d_in[12];
    const float* lnfw = (const float*)d_in[13];
    const float* lnfb = (const float*)d_in[14];

    float*  x     = (float*)d_ws;                       // [2048][768]  f32
    bf16_t* h     = (bf16_t*)(x + (size_t)M_ * D_);     // [2048][768]
    bf16_t* qkv   = h     + (size_t)M_ * D_;            // [2048][2304]
    bf16_t* y     = qkv   + (size_t)M_ * 3 * D_;        // [2048][768]
    bf16_t* mid   = y     + (size_t)M_ * D_;            // [2048][3072]
    bf16_t* tokb  = mid   + (size_t)M_ * F_;            // [1024][768]
    bf16_t* wqkvT = tokb  + (size_t)V_ * D_;            // [L][2304][768]
    bf16_t* woutT = wqkvT + (size_t)L_ * 3 * D_ * D_;   // [L][768][768]
    bf16_t* w1T   = woutT + (size_t)L_ * D_ * D_;       // [L][3072][768]
    bf16_t* w2T   = w1T   + (size_t)L_ * D_ * F_;       // [L][768][3072]

    embed_kernel<<<M_, 256, 0, stream>>>(ids, tok, pos, x);
    conv_kernel<<<(V_ * D_) / 1024, 256, 0, stream>>>(tok, tokb);

    // all-layer weight transposes upfront (z = layer): 4 launches instead of 32
    wtrans_kernel<<<dim3(3 * D_ / 32, D_ / 32, L_), 256, 0, stream>>>(qkvw, wqkvT, D_, 3 * D_);
    wtrans_kernel<<<dim3(D_ / 32, D_ / 32, L_), 256, 0, stream>>>(outw, woutT, D_, D_);
    wtrans_kernel<<<dim3(F_ / 32, D_ / 32, L_), 256, 0, stream>>>(w1, w1T, D_, F_);
    wtrans_kernel<<<dim3(D_ / 32, F_ / 32, L_), 256, 0, stream>>>(w2, w2T, F_, D_);

    for (int l = 0; l < L_; ++l) {
        const bf16_t* wq = wqkvT + (size_t)l * 3 * D_ * D_;
        const bf16_t* wo = woutT + (size_t)l * D_ * D_;
        const bf16_t* wf1 = w1T + (size_t)l * D_ * F_;
        const bf16_t* wf2 = w2T + (size_t)l * F_ * D_;

        ln_kernel<<<M_, 256, 0, stream>>>(x, l1w + l * D_, l1b + l * D_, h);
        gemm_bt128<false, false><<<dim3(3 * D_ / 128, M_ / 128), 256, 0, stream>>>(
            h, wq, nullptr, qkv, M_, 3 * D_, D_);
        attn_kernel<<<dim3(T_ / 64, B_ * H_), 256, 0, stream>>>(qkv, y);
        gemm_bt<64, true, false, false, true><<<dim3(D_ / 64, M_ / 64), 256, 0, stream>>>(
            y, wo, nullptr, x, x, M_, D_, D_);
        ln_kernel<<<M_, 256, 0, stream>>>(x, l2w + l * D_, l2b + l * D_, h);
        gemm_bt128<true, true><<<dim3(F_ / 128, M_ / 128), 256, 0, stream>>>(
            h, wf1, b1 + (size_t)l * F_, mid, M_, F_, D_);
        gemm_bt<64, true, true, false, true><<<dim3(D_ / 64, M_ / 64), 256, 0, stream>>>(
            mid, wf2, b2 + (size_t)l * D_, x, x, M_, D_, F_);
    }

    ln_kernel<<<M_, 256, 0, stream>>>(x, lnfw, lnfb, h);
    gemm_bt<64, false, false, false, true><<<dim3(V_ / 64, M_ / 64), 256, 0, stream>>>(
        h, tokb, nullptr, nullptr, d_out, M_, V_, D_);
}

// Round 5
// 1254.781 us; speedup vs baseline: 1.1113x; 1.1113x over previous
//
#include <hip/hip_runtime.h>
#include <hip/hip_bf16.h>
#include <math.h>

// ---- problem constants ----
#define D_  768
#define T_  1024
#define B_  2
#define H_  12
#define HD_ 64
#define L_  8
#define F_  3072
#define V_  1024
#define M_  (B_ * T_)   // 2048 rows of activations

typedef __bf16 bf16_t;
typedef __bf16 bf16x8 __attribute__((ext_vector_type(8)));
typedef float  f32x4  __attribute__((ext_vector_type(4)));

// async 16B global->LDS (direct DMA, lane i lands at lds_base + i*16)
__device__ __forceinline__ void ld_g2l16(const bf16_t* g, bf16_t* l)
{
    __builtin_amdgcn_global_load_lds(
        (const __attribute__((address_space(1))) void*)g,
        (__attribute__((address_space(3))) void*)l,
        16, 0, 0);
}

// ---- DPP16 rotate-reduce within each 16-lane group (pure VALU, no LDS pipe) ----
// row_ror:n ctrl = 0x120|n. After steps 1,2,4,8 every lane holds the full reduction.
template<int CTRL>
__device__ __forceinline__ float dpp_f32(float v)
{
    return __builtin_bit_cast(float,
        __builtin_amdgcn_update_dpp(0, __builtin_bit_cast(int, v),
                                    CTRL, 0xf, 0xf, true));
}
__device__ __forceinline__ float red16_max(float v)
{
    v = fmaxf(v, dpp_f32<0x121>(v));
    v = fmaxf(v, dpp_f32<0x122>(v));
    v = fmaxf(v, dpp_f32<0x124>(v));
    v = fmaxf(v, dpp_f32<0x128>(v));
    return v;
}
__device__ __forceinline__ float red16_sum(float v)
{
    v += dpp_f32<0x121>(v);
    v += dpp_f32<0x122>(v);
    v += dpp_f32<0x124>(v);
    v += dpp_f32<0x128>(v);
    return v;
}

// ---------------- embed: x = tok_emb[ids] + pos_emb (all f32) ----------------
__global__ __launch_bounds__(256) void embed_kernel(
    const int* __restrict__ ids, const float* __restrict__ tok,
    const float* __restrict__ pos, float* __restrict__ x)
{
    const int row = blockIdx.x;          // b*T + t
    const int t   = row & (T_ - 1);
    const int id  = ids[row];
    const int c   = threadIdx.x;
#pragma unroll
    for (int i = 0; i < 3; ++i) {
        const int d = c + i * 256;
        x[(size_t)row * D_ + d] = tok[(size_t)id * D_ + d] + pos[(size_t)t * D_ + d];
    }
}

// ------- weight transpose+convert: f32 [K][N] -> bf16 [N][K], per-layer via z -------
__global__ __launch_bounds__(256) void wtrans_kernel(
    const float* __restrict__ in, bf16_t* __restrict__ out, int K, int N)
{
    __shared__ float tile[32][33];
    const size_t loff = (size_t)blockIdx.z * K * N;
    const float* inp  = in  + loff;
    bf16_t*      outp = out + loff;
    const int n0 = blockIdx.x * 32, k0 = blockIdx.y * 32;
    const int tx = threadIdx.x & 31, ty = threadIdx.x >> 5;   // ty 0..7
#pragma unroll
    for (int i = 0; i < 4; ++i)
        tile[ty + 8 * i][tx] = inp[(size_t)(k0 + ty + 8 * i) * N + n0 + tx];
    __syncthreads();
#pragma unroll
    for (int i = 0; i < 4; ++i) {
        const int n = ty + 8 * i;
        outp[(size_t)(n0 + n) * K + k0 + tx] = (bf16_t)tile[tx][n];
    }
}

// ---------------- straight convert f32 -> bf16 (tok_emb for lm_head) ----------------
__global__ __launch_bounds__(256) void conv_kernel(
    const float* __restrict__ in, bf16_t* __restrict__ out)
{
    const int i = blockIdx.x * 1024 + threadIdx.x * 4;
    const f32x4 v = *(const f32x4*)(in + i);
#pragma unroll
    for (int j = 0; j < 4; ++j) out[i + j] = (bf16_t)v[j];
}

// ---------------- layernorm: f32 in -> bf16 out ----------------
__device__ __forceinline__ float block_sum(float v)
{
    __shared__ float sm[4];
#pragma unroll
    for (int off = 32; off; off >>= 1) v += __shfl_down(v, off);
    if ((threadIdx.x & 63) == 0) sm[threadIdx.x >> 6] = v;
    __syncthreads();
    const float r = sm[0] + sm[1] + sm[2] + sm[3];
    __syncthreads();
    return r;
}

__global__ __launch_bounds__(256) void ln_kernel(
    const float* __restrict__ x, const float* __restrict__ w,
    const float* __restrict__ b, bf16_t* __restrict__ out)
{
    const int row = blockIdx.x;
    const float* xr = x + (size_t)row * D_;
    const int t = threadIdx.x;
    const float v0 = xr[t];
    const float v1 = xr[t + 256];
    const float v2 = xr[t + 512];
    const float mu = block_sum(v0 + v1 + v2) * (1.f / D_);
    const float d0 = v0 - mu, d1 = v1 - mu, d2 = v2 - mu;
    const float var = block_sum(d0 * d0 + d1 * d1 + d2 * d2) * (1.f / D_);
    const float rstd = rsqrtf(var + 1e-5f);
    bf16_t* o = out + (size_t)row * D_;
    o[t]       = (bf16_t)(d0 * rstd * w[t]       + b[t]);
    o[t + 256] = (bf16_t)(d1 * rstd * w[t + 256] + b[t + 256]);
    o[t + 512] = (bf16_t)(d2 * rstd * w[t + 512] + b[t + 512]);
}

// ---------------- GEMM (B^T bf16): C[M,N] = act(A[M,K] @ Bt[N,K]^T + bias + res) ----
// BM=64, BK=64, BN in {64,128}; 4 waves in 2x2 quadrants, each wave 32 x BN/2.
// global_load_lds w=16, XOR-8 16B-chunk swizzle. XCD-aware bijective block remap
// (all grids here have nwg % 8 == 0): XCD x owns a contiguous tile range -> B/A
// panel reuse hits the XCD-private L2 instead of L3.
template<int BN, bool RES, bool BIAS, bool GELU_, bool OUTF32>
__global__ __launch_bounds__(256) void gemm_bt(
    const bf16_t* __restrict__ A, const bf16_t* __restrict__ Bt,
    const float* __restrict__ bias, const float* __restrict__ res,
    void* __restrict__ Cp, int M, int N, int K)
{
    constexpr int BM = 64, BK = 64;
    constexpr int WN = BN / 2, NT = WN / 16;
    constexpr int AR = (BM * BK) / (256 * 8);
    constexpr int BR = (BN * BK) / (256 * 8);
    __shared__ bf16_t As[BM * BK];
    __shared__ bf16_t Bs[BN * BK];

    const int t    = threadIdx.x;
    const int wave = t >> 6, lane = t & 63;
    const int lr   = lane & 15, quad = lane >> 4;

    // XCD swizzle: dispatch id -> contiguous tile id per XCD (bijective, nwg%8==0)
    const int nx  = gridDim.x;
    const int nwg = nx * gridDim.y;
    int id = blockIdx.y * nx + blockIdx.x;
    id = (id & 7) * (nwg >> 3) + (id >> 3);
    const int bn0 = (id % nx) * BN, bm0 = (id / nx) * BM;

    const int wm   = wave >> 1, wn = wave & 1;

    f32x4 acc[2][NT];
#pragma unroll
    for (int i = 0; i < 2; ++i)
#pragma unroll
        for (int j = 0; j < NT; ++j) { f32x4 z = {0.f, 0.f, 0.f, 0.f}; acc[i][j] = z; }

    const bf16_t* asrc[AR];
    const bf16_t* bsrc[BR];
#pragma unroll
    for (int rnd = 0; rnd < AR; ++rnd) {
        const int p = rnd * 256 + t, row = p >> 3, c = (p & 7) ^ (row & 7);
        asrc[rnd] = A + (size_t)(bm0 + row) * K + c * 8;
    }
#pragma unroll
    for (int rnd = 0; rnd < BR; ++rnd) {
        const int p = rnd * 256 + t, row = p >> 3, c = (p & 7) ^ (row & 7);
        bsrc[rnd] = Bt + (size_t)(bn0 + row) * K + c * 8;
    }

    for (int k0 = 0; k0 < K; k0 += BK) {
        __syncthreads();
#pragma unroll
        for (int rnd = 0; rnd < AR; ++rnd)
            ld_g2l16(asrc[rnd] + k0, As + (rnd * 256 + wave * 64) * 8);
#pragma unroll
        for (int rnd = 0; rnd < BR; ++rnd)
            ld_g2l16(bsrc[rnd] + k0, Bs + (rnd * 256 + wave * 64) * 8);
        __syncthreads();

#pragma unroll
        for (int ks = 0; ks < 2; ++ks) {
            const int ch = ((quad + 4 * ks) ^ (lr & 7)) * 8;
            const bf16x8 a0 = *(const bf16x8*)(As + (wm * 32 + lr) * BK + ch);
            const bf16x8 a1 = *(const bf16x8*)(As + (wm * 32 + 16 + lr) * BK + ch);
#pragma unroll
            for (int nt = 0; nt < NT; ++nt) {
                const bf16x8 b = *(const bf16x8*)(Bs + (wn * WN + nt * 16 + lr) * BK + ch);
                acc[0][nt] = __builtin_amdgcn_mfma_f32_16x16x32_bf16(a0, b, acc[0][nt], 0, 0, 0);
                acc[1][nt] = __builtin_amdgcn_mfma_f32_16x16x32_bf16(a1, b, acc[1][nt], 0, 0, 0);
            }
        }
    }

#pragma unroll
    for (int mt = 0; mt < 2; ++mt) {
        const int mbase = bm0 + wm * 32 + mt * 16 + quad * 4;
#pragma unroll
        for (int nt = 0; nt < NT; ++nt) {
            const int n = bn0 + wn * WN + nt * 16 + lr;
            const float bv = BIAS ? bias[n] : 0.f;
#pragma unroll
            for (int r = 0; r < 4; ++r) {
                const int m = mbase + r;
                float v = acc[mt][nt][r] + bv;
                if (RES)   v += res[(size_t)m * N + n];
                if (GELU_) v = 0.5f * v * (1.f + erff(v * 0.70710678118654752f));
                if (OUTF32) ((float*)Cp)[(size_t)m * N + n] = v;
                else        ((bf16_t*)Cp)[(size_t)m * N + n] = (bf16_t)v;
            }
        }
    }
}

// ---------------- flash attention, MFMA ----------------
// v5: T14 register prefetch + heavy-tile-first + DPP16 rotate-reduce softmax
// (replaces 32 ds_bpermute/iter with VALU row_ror ops; LDS pipe was the
// per-iteration bottleneck).
__global__ __launch_bounds__(256) void attn_kernel(
    const bf16_t* __restrict__ qkv, bf16_t* __restrict__ y)
{
    __shared__ bf16_t Ks[64][72];
    __shared__ bf16_t Vt[64][72];
    __shared__ bf16_t Ps[4][16][72];

    const int qt   = (int)gridDim.x - 1 - (int)blockIdx.x;   // heavy first
    const int q0   = qt * 64;
    const int bh   = blockIdx.y;
    const int b    = bh / H_;
    const int hh   = bh % H_;
    const int t    = threadIdx.x;
    const int wave = t >> 6;
    const int lane = t & 63;
    const int lr   = lane & 15;
    const int quad = lane >> 4;

    const size_t qg = ((size_t)b * T_ + q0 + wave * 16 + lr) * (3 * D_) + hh * HD_;
    const bf16x8 aQ0 = *(const bf16x8*)(qkv + qg + quad * 8);
    const bf16x8 aQ1 = *(const bf16x8*)(qkv + qg + 32 + quad * 8);

    const size_t rowb  = (size_t)b * T_;
    const size_t tstep = (size_t)64 * 3 * D_;
    const int    kkey  = t >> 2, kdc = (t & 3) * 8;
    const bf16_t* kptr = qkv + (rowb + kkey) * (3 * D_) + D_ + hh * HD_ + kdc;
    const bf16_t* vptr = qkv + (rowb + lane) * (3 * D_) + 2 * D_ + hh * HD_ + wave * 16;

    bf16x8 rk0 = *(const bf16x8*)(kptr);
    bf16x8 rk1 = *(const bf16x8*)(kptr + 32);
    bf16x8 rv0 = *(const bf16x8*)(vptr);
    bf16x8 rv1 = *(const bf16x8*)(vptr + 8);

    f32x4 o[4];
#pragma unroll
    for (int i = 0; i < 4; ++i) { f32x4 z = {0.f, 0.f, 0.f, 0.f}; o[i] = z; }
    float mrow[4] = {-1e30f, -1e30f, -1e30f, -1e30f};
    float lrow[4] = {0.f, 0.f, 0.f, 0.f};

    for (int kt = 0; kt <= qt; ++kt) {
        const int k_base = kt * 64;
        __syncthreads();

        *(bf16x8*)(&Ks[kkey][kdc])      = rk0;
        *(bf16x8*)(&Ks[kkey][kdc + 32]) = rk1;
#pragma unroll
        for (int i = 0; i < 8; ++i) {
            Vt[wave * 16 + i][lane]     = rv0[i];
            Vt[wave * 16 + 8 + i][lane] = rv1[i];
        }
        __syncthreads();

        if (kt < qt) {
            const bf16_t* kp = kptr + (size_t)(kt + 1) * tstep;
            const bf16_t* vp = vptr + (size_t)(kt + 1) * tstep;
            rk0 = *(const bf16x8*)(kp);
            rk1 = *(const bf16x8*)(kp + 32);
            rv0 = *(const bf16x8*)(vp);
            rv1 = *(const bf16x8*)(vp + 8);
        }

        f32x4 s[4];
#pragma unroll
        for (int i = 0; i < 4; ++i) { f32x4 z = {0.f, 0.f, 0.f, 0.f}; s[i] = z; }
#pragma unroll
        for (int nt = 0; nt < 4; ++nt) {
            bf16x8 bk0 = *(const bf16x8*)(&Ks[nt * 16 + lr][quad * 8]);
            bf16x8 bk1 = *(const bf16x8*)(&Ks[nt * 16 + lr][32 + quad * 8]);
            s[nt] = __builtin_amdgcn_mfma_f32_16x16x32_bf16(aQ0, bk0, s[nt], 0, 0, 0);
            s[nt] = __builtin_amdgcn_mfma_f32_16x16x32_bf16(aQ1, bk1, s[nt], 0, 0, 0);
        }

        // ---- online softmax: DPP16 reductions over the 16-lane (lr) groups ----
#pragma unroll
        for (int r = 0; r < 4; ++r) {
            const int qg_i = q0 + wave * 16 + quad * 4 + r;
            float mx = -1e30f;
#pragma unroll
            for (int nt = 0; nt < 4; ++nt) {
                float sv = s[nt][r] * 0.125f;
                if (k_base + nt * 16 + lr > qg_i) sv = -1e30f;
                s[nt][r] = sv;
                mx = fmaxf(mx, sv);
            }
            mx = red16_max(mx);
            const float mnew = fmaxf(mrow[r], mx);
            float ps = 0.f;
#pragma unroll
            for (int nt = 0; nt < 4; ++nt) {
                const float p = __expf(s[nt][r] - mnew);
                s[nt][r] = p;
                ps += p;
            }
            ps = red16_sum(ps);
            const float alpha = __expf(mrow[r] - mnew);
            lrow[r] = lrow[r] * alpha + ps;
            mrow[r] = mnew;
#pragma unroll
            for (int nt = 0; nt < 4; ++nt) o[nt][r] *= alpha;
        }

#pragma unroll
        for (int nt = 0; nt < 4; ++nt)
#pragma unroll
            for (int r = 0; r < 4; ++r)
                Ps[wave][quad * 4 + r][nt * 16 + lr] = (bf16_t)s[nt][r];

        const bf16x8 aP0 = *(const bf16x8*)(&Ps[wave][lr][quad * 8]);
        const bf16x8 aP1 = *(const bf16x8*)(&Ps[wave][lr][32 + quad * 8]);
#pragma unroll
        for (int nt = 0; nt < 4; ++nt) {
            bf16x8 bv0 = *(const bf16x8*)(&Vt[nt * 16 + lr][quad * 8]);
            bf16x8 bv1 = *(const bf16x8*)(&Vt[nt * 16 + lr][32 + quad * 8]);
            o[nt] = __builtin_amdgcn_mfma_f32_16x16x32_bf16(aP0, bv0, o[nt], 0, 0, 0);
            o[nt] = __builtin_amdgcn_mfma_f32_16x16x32_bf16(aP1, bv1, o[nt], 0, 0, 0);
        }
    }

#pragma unroll
    for (int r = 0; r < 4; ++r) {
        const float inv = 1.f / lrow[r];
        const size_t row = (size_t)b * T_ + q0 + wave * 16 + quad * 4 + r;
#pragma unroll
        for (int nt = 0; nt < 4; ++nt)
            y[row * D_ + hh * HD_ + nt * 16 + lr] = (bf16_t)(o[nt][r] * inv);
    }
}

// ---------------- launch ----------------
extern "C" void kernel_launch(void* const* d_in, const int* in_sizes, int n_in,
                              void* d_out, int out_size, void* d_ws, size_t ws_size,
                              hipStream_t stream)
{
    const int*   ids  = (const int*)d_in[0];
    const float* tok  = (const float*)d_in[1];
    const float* pos  = (const float*)d_in[2];
    const float* l1w  = (const float*)d_in[3];
    const float* l1b  = (const float*)d_in[4];
    const float* qkvw = (const float*)d_in[5];
    const float* outw = (const float*)d_in[6];
    const float* l2w  = (const float*)d_in[7];
    const float* l2b  = (const float*)d_in[8];
    const float* w1   = (const float*)d_in[9];
    const float* b1   = (const float*)d_in[10];
    const float* w2   = (const float*)d_in[11];
    const float* b2   = (const float*)d_in[12];
    const float* lnfw = (const float*)d_in[13];
    const float* lnfb = (const float*)d_in[14];

    float*  x     = (float*)d_ws;                       // [2048][768]  f32
    bf16_t* h     = (bf16_t*)(x + (size_t)M_ * D_);     // [2048][768]
    bf16_t* qkv   = h     + (size_t)M_ * D_;            // [2048][2304]
    bf16_t* y     = qkv   + (size_t)M_ * 3 * D_;        // [2048][768]
    bf16_t* mid   = y     + (size_t)M_ * D_;            // [2048][3072]
    bf16_t* tokb  = mid   + (size_t)M_ * F_;            // [1024][768]
    bf16_t* wqkvT = tokb  + (size_t)V_ * D_;            // [L][2304][768]
    bf16_t* woutT = wqkvT + (size_t)L_ * 3 * D_ * D_;   // [L][768][768]
    bf16_t* w1T   = woutT + (size_t)L_ * D_ * D_;       // [L][3072][768]
    bf16_t* w2T   = w1T   + (size_t)L_ * D_ * F_;       // [L][768][3072]

    embed_kernel<<<M_, 256, 0, stream>>>(ids, tok, pos, x);
    conv_kernel<<<(V_ * D_) / 1024, 256, 0, stream>>>(tok, tokb);

    // all-layer weight transposes upfront (z = layer): 4 launches instead of 32
    wtrans_kernel<<<dim3(3 * D_ / 32, D_ / 32, L_), 256, 0, stream>>>(qkvw, wqkvT, D_, 3 * D_);
    wtrans_kernel<<<dim3(D_ / 32, D_ / 32, L_), 256, 0, stream>>>(outw, woutT, D_, D_);
    wtrans_kernel<<<dim3(F_ / 32, D_ / 32, L_), 256, 0, stream>>>(w1, w1T, D_, F_);
    wtrans_kernel<<<dim3(D_ / 32, F_ / 32, L_), 256, 0, stream>>>(w2, w2T, F_, D_);

    for (int l = 0; l < L_; ++l) {
        const bf16_t* wq  = wqkvT + (size_t)l * 3 * D_ * D_;
        const bf16_t* wo  = woutT + (size_t)l * D_ * D_;
        const bf16_t* wf1 = w1T   + (size_t)l * D_ * F_;
        const bf16_t* wf2 = w2T   + (size_t)l * F_ * D_;

        ln_kernel<<<M_, 256, 0, stream>>>(x, l1w + l * D_, l1b + l * D_, h);
        gemm_bt<128, false, false, false, false><<<dim3(3 * D_ / 128, M_ / 64), 256, 0, stream>>>(
            h, wq, nullptr, nullptr, qkv, M_, 3 * D_, D_);
        attn_kernel<<<dim3(T_ / 64, B_ * H_), 256, 0, stream>>>(qkv, y);
        gemm_bt<64, true, false, false, true><<<dim3(D_ / 64, M_ / 64), 256, 0, stream>>>(
            y, wo, nullptr, x, x, M_, D_, D_);
        ln_kernel<<<M_, 256, 0, stream>>>(x, l2w + l * D_, l2b + l * D_, h);
        gemm_bt<128, false, true, true, false><<<dim3(F_ / 128, M_ / 64), 256, 0, stream>>>(
            h, wf1, b1 + (size_t)l * F_, nullptr, mid, M_, F_, D_);
        gemm_bt<64, true, true, false, true><<<dim3(D_ / 64, M_ / 64), 256, 0, stream>>>(
            mid, wf2, b2 + (size_t)l * D_, x, x, M_, D_, F_);
    }

    ln_kernel<<<M_, 256, 0, stream>>>(x, lnfw, lnfb, h);
    gemm_bt<64, false, false, false, true><<<dim3(V_ / 64, M_ / 64), 256, 0, stream>>>(
        h, tokb, nullptr, nullptr, d_out, M_, V_, D_);
}